// Round 4
// baseline (546.369 us; speedup 1.0000x reference)
//
#include <hip/hip_runtime.h>
#include <hip/hip_bf16.h>

constexpr int B_ = 2, HQ_ = 16, HP_ = 8, S_ = 2048, D_ = 64, DV_ = 128;
constexpr float LAMB0 = 0.8f;
constexpr float EPSV = 1e-5f;

constexpr int TQ = 64, TK = 32;
constexpr int VSTR = 40;  // shorts per V^T row (32 + 8 pad) = 80 B, 16B-aligned

typedef __attribute__((ext_vector_type(8))) short bf16x8;
typedef __attribute__((ext_vector_type(4))) float f32x4;
typedef __attribute__((ext_vector_type(4))) short short4v;

__device__ __forceinline__ unsigned short f2bf(float x) {
  unsigned u = __float_as_uint(x);
  u += 0x7FFFu + ((u >> 16) & 1u);  // RNE
  return (unsigned short)(u >> 16);
}
__device__ __forceinline__ float bf2f(unsigned short h) {
  return __uint_as_float((unsigned)h << 16);
}
__device__ __forceinline__ unsigned pack2(unsigned short a, unsigned short b) {
  return (unsigned)a | ((unsigned)b << 16);
}

// ---------------------------------------------------------------------------
// Differential flash attention, bf16x3 MFMA emulation.
// R4 structure: K read directly from global (L2/L3-resident, shared by 32
// blocks) -> no K LDS; V double-buffered in LDS (41KB); P-exchange through a
// per-wave LDS slice (8 ds_write_b64 + 4 ds_read_b128, intra-wave) replacing
// 32 ds_bpermute; LDS 51.2KB -> 3 blocks/CU (3 waves/SIMD).
// gn_stats fused into epilogue (one stat region per block).
// ---------------------------------------------------------------------------
__launch_bounds__(256, 3)
__global__ void diffattn_fwd(const float* __restrict__ qg, const float* __restrict__ kg,
                             const float* __restrict__ vg,
                             const float* __restrict__ lq1, const float* __restrict__ lk1,
                             const float* __restrict__ lq2, const float* __restrict__ lk2,
                             float* __restrict__ Obuf, float* __restrict__ stats) {
  __shared__ short Vt[2][2][DV_][VSTR];  // [buf][hi/lo][dv][k] 40.96 KB
  __shared__ short Pex[4][32][40];       // per-wave P exchange: rows 0-15 hi, 16-31 lo
  __shared__ float redbuf[8];

  const int tid = threadIdx.x;
  const int w = tid >> 6;
  const int l = tid & 63;
  const int g = l >> 4;
  const int li = l & 15;

  const int t = blockIdx.x;
  const int bh = t & 15;
  const int b = bh >> 3;
  const int hp = bh & 7;
  const int u = t >> 4;
  const int qt = (u & 1) ? (31 - (u >> 1)) : (u >> 1);
  const int q0 = qt * TQ;
  const int qw = q0 + w * 16;

  float d1 = 0.f, d2 = 0.f;
  for (int i = 0; i < D_; ++i) { d1 += lq1[i] * lk1[i]; d2 += lq2[i] * lk2[i]; }
  const float lam = __expf(d1) - __expf(d2) + LAMB0;

  // ---- Q fragments in registers, hi/lo split ----
  bf16x8 qhi[2][2], qlo[2][2];
#pragma unroll
  for (int h = 0; h < 2; ++h)
#pragma unroll
    for (int c = 0; c < 2; ++c) {
      const float* p = qg + (((size_t)b * HQ_ + 2 * hp + h) * S_ + qw + li) * D_ + c * 32 + g * 8;
      float4 a = *reinterpret_cast<const float4*>(p);
      float4 bq = *reinterpret_cast<const float4*>(p + 4);
      float xs[8] = {a.x, a.y, a.z, a.w, bq.x, bq.y, bq.z, bq.w};
      union { bf16x8 v; unsigned us[4]; } H, L;
#pragma unroll
      for (int j = 0; j < 4; ++j) {
        unsigned short h0 = f2bf(xs[2 * j]), h1 = f2bf(xs[2 * j + 1]);
        H.us[j] = pack2(h0, h1);
        L.us[j] = pack2(f2bf(xs[2 * j] - bf2f(h0)), f2bf(xs[2 * j + 1] - bf2f(h1)));
      }
      qhi[h][c] = H.v;
      qlo[h][c] = L.v;
    }

  float mreg[2] = {0.f, 0.f};  // ghostmax init: m=0, l=1 (implicit zero logit)
  float lreg[2] = {1.f, 1.f};
  const f32x4 zero4 = {0.f, 0.f, 0.f, 0.f};
  f32x4 Oacc[2][8];
#pragma unroll
  for (int h = 0; h < 2; ++h)
#pragma unroll
    for (int d = 0; d < 8; ++d) Oacc[h][d] = zero4;

  // V staging role
  const int vdv = tid & 127;
  const int vkq0 = tid >> 7;
  const float* vb0 = vg + ((size_t)b * HP_ + hp) * S_ * DV_ + vdv;
  float vreg[16];

  auto issue_v = [&](int k0) {
    const float* vb = vb0 + (size_t)k0 * DV_;
#pragma unroll
    for (int it = 0; it < 4; ++it) {
      int kq = vkq0 + 2 * it;
#pragma unroll
      for (int c = 0; c < 4; ++c) vreg[it * 4 + c] = vb[(size_t)(kq * 4 + c) * DV_];
    }
  };
  auto write_v = [&](int bufp) {
#pragma unroll
    for (int it = 0; it < 4; ++it) {
      int kq = vkq0 + 2 * it;
      float x0 = vreg[it * 4 + 0], x1 = vreg[it * 4 + 1];
      float x2 = vreg[it * 4 + 2], x3 = vreg[it * 4 + 3];
      unsigned short h0 = f2bf(x0), h1 = f2bf(x1), h2 = f2bf(x2), h3 = f2bf(x3);
      short4v hi = {(short)h0, (short)h1, (short)h2, (short)h3};
      short4v lo = {(short)f2bf(x0 - bf2f(h0)), (short)f2bf(x1 - bf2f(h1)),
                    (short)f2bf(x2 - bf2f(h2)), (short)f2bf(x3 - bf2f(h3))};
      *reinterpret_cast<short4v*>(&Vt[bufp][0][vdv][kq * 4]) = hi;
      *reinterpret_cast<short4v*>(&Vt[bufp][1][vdv][kq * 4]) = lo;
    }
  };

  const int nkt = (q0 + TQ) / TK;

  issue_v(0);
  write_v(0);
  __syncthreads();

  for (int kt = 0; kt < nkt; ++kt) {
    const int k0 = kt * TK;
    const int p_ = kt & 1;

    if (kt + 1 < nkt) issue_v((kt + 1) * TK);

    if (k0 <= qw + 15) {
      const bool needmask = (k0 + TK - 1 > qw);
      const int qglob = qw + li;
      bf16x8 AH[2], AL[2];

#pragma unroll
      for (int h = 0; h < 2; ++h) {
        // ---- K direct from global: rows k0+ms*16+li, cols c*32+g*8 ----
        const float* kb = kg + (((size_t)b * HQ_ + 2 * hp + h) * S_ + k0 + li) * D_ + g * 8;
        f32x4 sT[2] = {zero4, zero4};
#pragma unroll
        for (int ms = 0; ms < 2; ++ms) {
          float4 kA[4];
#pragma unroll
          for (int cc = 0; cc < 2; ++cc) {
            const float* p = kb + (size_t)(ms * 16) * D_ + cc * 32;
            kA[cc * 2 + 0] = *reinterpret_cast<const float4*>(p);
            kA[cc * 2 + 1] = *reinterpret_cast<const float4*>(p + 4);
          }
          bf16x8 khi[2], klo[2];
#pragma unroll
          for (int cc = 0; cc < 2; ++cc) {
            float xs[8] = {kA[cc * 2].x,     kA[cc * 2].y,     kA[cc * 2].z,     kA[cc * 2].w,
                           kA[cc * 2 + 1].x, kA[cc * 2 + 1].y, kA[cc * 2 + 1].z, kA[cc * 2 + 1].w};
            union { bf16x8 v; unsigned us[4]; } H, L;
#pragma unroll
            for (int j = 0; j < 4; ++j) {
              unsigned short h0 = f2bf(xs[2 * j]), h1 = f2bf(xs[2 * j + 1]);
              H.us[j] = pack2(h0, h1);
              L.us[j] = pack2(f2bf(xs[2 * j] - bf2f(h0)), f2bf(xs[2 * j + 1] - bf2f(h1)));
            }
            khi[cc] = H.v;
            klo[cc] = L.v;
          }
          __builtin_amdgcn_s_setprio(1);
#pragma unroll
          for (int cc = 0; cc < 2; ++cc) {
            sT[ms] = __builtin_amdgcn_mfma_f32_16x16x32_bf16(khi[cc], qhi[h][cc], sT[ms], 0, 0, 0);
            sT[ms] = __builtin_amdgcn_mfma_f32_16x16x32_bf16(khi[cc], qlo[h][cc], sT[ms], 0, 0, 0);
            sT[ms] = __builtin_amdgcn_mfma_f32_16x16x32_bf16(klo[cc], qhi[h][cc], sT[ms], 0, 0, 0);
          }
          __builtin_amdgcn_s_setprio(0);
        }

        // ---- online ghostmax, head h (lane holds q=li, k=16ms+4g+r) ----
        float sv[2][4];
#pragma unroll
        for (int ms = 0; ms < 2; ++ms)
#pragma unroll
          for (int r = 0; r < 4; ++r) {
            float v = sT[ms][r] * 0.125f;
            if (needmask && (k0 + ms * 16 + g * 4 + r > qglob)) v = -1e30f;
            sv[ms][r] = v;
          }
        float tmax = fmaxf(fmaxf(fmaxf(sv[0][0], sv[0][1]), fmaxf(sv[0][2], sv[0][3])),
                           fmaxf(fmaxf(sv[1][0], sv[1][1]), fmaxf(sv[1][2], sv[1][3])));
        tmax = fmaxf(tmax, __shfl_xor(tmax, 16));
        tmax = fmaxf(tmax, __shfl_xor(tmax, 32));

        if (__any(tmax > mreg[h] + 8.f)) {  // defer-max: rescale rarely
          const float mnew = fmaxf(mreg[h], tmax);
          const float fh = __expf(mreg[h] - mnew);
          mreg[h] = mnew;
          lreg[h] *= fh;
          float fr[4];
#pragma unroll
          for (int r = 0; r < 4; ++r) fr[r] = __shfl(fh, 20 * g + r);
#pragma unroll
          for (int d = 0; d < 8; ++d) {
            f32x4 o = Oacc[h][d];
            o[0] *= fr[0]; o[1] *= fr[1]; o[2] *= fr[2]; o[3] *= fr[3];
            Oacc[h][d] = o;
          }
        }

        float p[2][4], psum = 0.f;
#pragma unroll
        for (int ms = 0; ms < 2; ++ms)
#pragma unroll
          for (int r = 0; r < 4; ++r) {
            p[ms][r] = __expf(sv[ms][r] - mreg[h]);
            psum += p[ms][r];
          }
        psum += __shfl_xor(psum, 16);
        psum += __shfl_xor(psum, 32);
        lreg[h] += psum;

        // ---- P -> bf16 hi/lo through per-wave LDS slice (short idx == k) ----
        {
          union { unsigned uu[2]; short4v s; } W;
          W.uu[0] = pack2(f2bf(p[0][0]), f2bf(p[0][1]));
          W.uu[1] = pack2(f2bf(p[0][2]), f2bf(p[0][3]));
          *reinterpret_cast<short4v*>(&Pex[w][li][g * 4]) = W.s;
          W.uu[0] = pack2(f2bf(p[1][0]), f2bf(p[1][1]));
          W.uu[1] = pack2(f2bf(p[1][2]), f2bf(p[1][3]));
          *reinterpret_cast<short4v*>(&Pex[w][li][16 + g * 4]) = W.s;
          float pl[2][4];
#pragma unroll
          for (int ms = 0; ms < 2; ++ms)
#pragma unroll
            for (int r = 0; r < 4; ++r) pl[ms][r] = p[ms][r] - bf2f(f2bf(p[ms][r]));
          W.uu[0] = pack2(f2bf(pl[0][0]), f2bf(pl[0][1]));
          W.uu[1] = pack2(f2bf(pl[0][2]), f2bf(pl[0][3]));
          *reinterpret_cast<short4v*>(&Pex[w][16 + li][g * 4]) = W.s;
          W.uu[0] = pack2(f2bf(pl[1][0]), f2bf(pl[1][1]));
          W.uu[1] = pack2(f2bf(pl[1][2]), f2bf(pl[1][3]));
          *reinterpret_cast<short4v*>(&Pex[w][16 + li][16 + g * 4]) = W.s;
        }
        AH[h] = *reinterpret_cast<const bf16x8*>(&Pex[w][li][g * 8]);
        AL[h] = *reinterpret_cast<const bf16x8*>(&Pex[w][16 + li][g * 8]);
      }

      // ---- PV: O += P * V (Ph*Vh + Pl*Vh + Ph*Vl) ----
      __builtin_amdgcn_s_setprio(1);
#pragma unroll
      for (int dvt = 0; dvt < 8; ++dvt) {
        bf16x8 vh = *reinterpret_cast<const bf16x8*>(&Vt[p_][0][dvt * 16 + li][g * 8]);
        bf16x8 vl = *reinterpret_cast<const bf16x8*>(&Vt[p_][1][dvt * 16 + li][g * 8]);
#pragma unroll
        for (int h = 0; h < 2; ++h) {
          f32x4 acc = Oacc[h][dvt];
          acc = __builtin_amdgcn_mfma_f32_16x16x32_bf16(AH[h], vh, acc, 0, 0, 0);
          acc = __builtin_amdgcn_mfma_f32_16x16x32_bf16(AL[h], vh, acc, 0, 0, 0);
          acc = __builtin_amdgcn_mfma_f32_16x16x32_bf16(AH[h], vl, acc, 0, 0, 0);
          Oacc[h][dvt] = acc;
        }
      }
      __builtin_amdgcn_s_setprio(0);
    }

    if (kt + 1 < nkt) {
      write_v((kt + 1) & 1);
      __syncthreads();
    }
  }

  // ---- epilogue: combine heads, store, fused GroupNorm partial stats ----
  float rl0[4], rl1[4];
#pragma unroll
  for (int r = 0; r < 4; ++r) {
    rl0[r] = 1.f / __shfl(lreg[0], 20 * g + r);
    rl1[r] = lam / __shfl(lreg[1], 20 * g + r);
  }
  float* ob = Obuf + ((size_t)(b * HP_ + hp)) * S_ * DV_;
  float lsum = 0.f, lss = 0.f;
#pragma unroll
  for (int dvt = 0; dvt < 8; ++dvt)
#pragma unroll
    for (int r = 0; r < 4; ++r) {
      float vres = Oacc[0][dvt][r] * rl0[r] - Oacc[1][dvt][r] * rl1[r];
      ob[(size_t)(qw + g * 4 + r) * DV_ + dvt * 16 + li] = vres;
      lsum += vres;
      lss += vres * vres;
    }
#pragma unroll
  for (int o = 1; o < 64; o <<= 1) {
    lsum += __shfl_xor(lsum, o);
    lss += __shfl_xor(lss, o);
  }
  if (l == 0) {
    redbuf[w * 2] = lsum;
    redbuf[w * 2 + 1] = lss;
  }
  __syncthreads();
  if (tid == 0) {
    const int region = ((b * HP_ + hp) << 1) | (q0 >= 1024 ? 1 : 0);
    atomicAdd(&stats[2 * region + 0], redbuf[0] + redbuf[2] + redbuf[4] + redbuf[6]);
    atomicAdd(&stats[2 * region + 1], redbuf[1] + redbuf[3] + redbuf[5] + redbuf[7]);
  }
}

// ---------------------------------------------------------------------------
// GroupNorm apply (stats produced by attn epilogue; 32 regions of 131072).
// ---------------------------------------------------------------------------
__global__ void gn_apply(const float* __restrict__ O, const float* __restrict__ stats,
                         const float* __restrict__ gw, const float* __restrict__ gb,
                         float* __restrict__ out) {
  const size_t f = ((size_t)blockIdx.x * 256 + threadIdx.x) * 4;
  const int g = (int)(f >> 17);
  const int sidx = (int)((f >> 7) & 2047);
  const int hp = (int)((f >> 18) & 7);
  const int c = hp * 128 + (sidx >> 4);
  const float mean = stats[2 * g + 0] * (1.f / 131072.f);
  const float var = stats[2 * g + 1] * (1.f / 131072.f) - mean * mean;
  const float sc = rsqrtf(var + EPSV) * gw[c] * 0.2f;  // fold (1 - lambda_init)
  const float bi = gb[c] * 0.2f;
  float4 x = *reinterpret_cast<const float4*>(O + f);
  float4 y;
  y.x = (x.x - mean) * sc + bi;
  y.y = (x.y - mean) * sc + bi;
  y.z = (x.z - mean) * sc + bi;
  y.w = (x.w - mean) * sc + bi;
  *reinterpret_cast<float4*>(out + f) = y;
}

extern "C" void kernel_launch(void* const* d_in, const int* in_sizes, int n_in,
                              void* d_out, int out_size, void* d_ws, size_t ws_size,
                              hipStream_t stream) {
  const float* q = (const float*)d_in[0];
  const float* k = (const float*)d_in[1];
  const float* v = (const float*)d_in[2];
  const float* lq1 = (const float*)d_in[3];
  const float* lk1 = (const float*)d_in[4];
  const float* lq2 = (const float*)d_in[5];
  const float* lk2 = (const float*)d_in[6];
  const float* gw = (const float*)d_in[7];
  const float* gb = (const float*)d_in[8];
  float* out = (float*)d_out;

  float* Obuf = (float*)d_ws;  // [B][HP][S][DV] fp32 = 16 MiB
  float* stats = (float*)((char*)d_ws + (size_t)B_ * HP_ * S_ * DV_ * sizeof(float));

  hipMemsetAsync(stats, 0, 64 * sizeof(float), stream);
  diffattn_fwd<<<dim3(512), dim3(256), 0, stream>>>(q, k, v, lq1, lk1, lq2, lk2, Obuf, stats);
  gn_apply<<<dim3(4096), dim3(256), 0, stream>>>(Obuf, stats, gw, gb, out);
}

// Round 5
// 478.450 us; speedup vs baseline: 1.1420x; 1.1420x over previous
//
#include <hip/hip_runtime.h>
#include <hip/hip_bf16.h>

constexpr int B_ = 2, HQ_ = 16, HP_ = 8, S_ = 2048, D_ = 64, DV_ = 128;
constexpr float LAMB0 = 0.8f;
constexpr float EPSV = 1e-5f;

constexpr int TQ = 64, TK = 32;
constexpr int KSTR = 72;  // shorts per K row (64+8) = 144 B = 16Bx9 (odd) -> uniform banks
constexpr int VSTR = 40;  // shorts per V^T row (32+8) = 80 B = 16Bx5 (odd) -> uniform banks

typedef __attribute__((ext_vector_type(8))) short bf16x8;
typedef __attribute__((ext_vector_type(4))) float f32x4;

__device__ __forceinline__ unsigned short f2bf(float x) {
  __hip_bfloat16 h = __float2bfloat16(x);  // RNE; compiler pairs into v_cvt_pk_bf16_f32
  unsigned short u;
  __builtin_memcpy(&u, &h, 2);
  return u;
}
__device__ __forceinline__ float bf2f(unsigned short h) {
  return __uint_as_float((unsigned)h << 16);
}
__device__ __forceinline__ unsigned pack2(unsigned short a, unsigned short b) {
  return (unsigned)a | ((unsigned)b << 16);
}
__device__ __forceinline__ void split8(const float* xs, bf16x8& hi, bf16x8& lo) {
  union { bf16x8 v; unsigned short s[8]; } H, L;
#pragma unroll
  for (int j = 0; j < 8; ++j) {
    unsigned short h = f2bf(xs[j]);
    H.s[j] = h;
    L.s[j] = f2bf(xs[j] - bf2f(h));
  }
  hi = H.v;
  lo = L.v;
}

// ---------------------------------------------------------------------------
// Differential flash attention, bf16x3 MFMA emulation.
// R5: cooperative K+V staging, SINGLE-buffered (49.2 KB LDS -> 3 blocks/CU),
// T14 issue-early global loads held in regs across compute; native cvt_pk
// bf16 converts; V^T staged b128 with XOR bank swizzle; P exchange through
// per-wave LDS slice; gn_stats fused into epilogue.
// ---------------------------------------------------------------------------
__launch_bounds__(256, 3)
__global__ void diffattn_fwd(const float* __restrict__ qg, const float* __restrict__ kg,
                             const float* __restrict__ vg,
                             const float* __restrict__ lq1, const float* __restrict__ lk1,
                             const float* __restrict__ lq2, const float* __restrict__ lk2,
                             float* __restrict__ Obuf, float* __restrict__ stats) {
  __shared__ short Kl[2][2][TK][KSTR];  // [head][hi/lo][k][d] 18.4 KB
  __shared__ short Vt[2][DV_][VSTR];    // [hi/lo][dv][k^swz]  20.5 KB
  __shared__ short Pex[4][32][40];      // per-wave P exchange 10.2 KB
  __shared__ float redbuf[8];

  const int tid = threadIdx.x;
  const int w = tid >> 6;
  const int l = tid & 63;
  const int g = l >> 4;
  const int li = l & 15;

  const int t = blockIdx.x;
  const int bh = t & 15;
  const int b = bh >> 3;
  const int hp = bh & 7;
  const int u = t >> 4;
  const int qt = (u & 1) ? (31 - (u >> 1)) : (u >> 1);  // causal load pairing
  const int q0 = qt * TQ;
  const int qw = q0 + w * 16;

  float d1 = 0.f, d2 = 0.f;
  for (int i = 0; i < D_; ++i) { d1 += lq1[i] * lk1[i]; d2 += lq2[i] * lk2[i]; }
  const float lam = __expf(d1) - __expf(d2) + LAMB0;

  // ---- Q fragments in registers, hi/lo split ----
  bf16x8 qhi[2][2], qlo[2][2];
#pragma unroll
  for (int h = 0; h < 2; ++h)
#pragma unroll
    for (int c = 0; c < 2; ++c) {
      const float* p = qg + (((size_t)b * HQ_ + 2 * hp + h) * S_ + qw + li) * D_ + c * 32 + g * 8;
      float4 a = *reinterpret_cast<const float4*>(p);
      float4 bq = *reinterpret_cast<const float4*>(p + 4);
      float xs[8] = {a.x, a.y, a.z, a.w, bq.x, bq.y, bq.z, bq.w};
      split8(xs, qhi[h][c], qlo[h][c]);
    }

  float mreg[2] = {0.f, 0.f};  // ghostmax init m=0, l=1 (implicit zero logit)
  float lreg[2] = {1.f, 1.f};
  const f32x4 zero4 = {0.f, 0.f, 0.f, 0.f};
  f32x4 Oacc[2][8];
#pragma unroll
  for (int h = 0; h < 2; ++h)
#pragma unroll
    for (int d = 0; d < 8; ++d) Oacc[h][d] = zero4;

  // staging roles
  const int khs = tid >> 7;          // K: head
  const int ktf = tid & 127;         //    128 threads cover 32x64 via b128 rows
  const float* kb0 = kg + ((size_t)b * HQ_ + 2 * hp + khs) * S_ * D_;
  const int vdv = tid & 127;         // V: dv lane
  const int vkq0 = tid >> 7;
  const float* vb0 = vg + ((size_t)b * HP_ + hp) * S_ * DV_ + vdv;
  const int vswz = ((vdv >> 3) & 3) << 3;

  float4 kreg[4];
  float vreg[16];

  auto issue_loads = [&](int k0) {
    const float* kb = kb0 + (size_t)k0 * D_;
#pragma unroll
    for (int it = 0; it < 2; ++it) {
      const float* p = kb + (size_t)((ktf >> 3) + it * 16) * D_ + (ktf & 7) * 8;
      kreg[it * 2 + 0] = *reinterpret_cast<const float4*>(p);
      kreg[it * 2 + 1] = *reinterpret_cast<const float4*>(p + 4);
    }
    const float* vb = vb0 + (size_t)k0 * DV_;
#pragma unroll
    for (int it = 0; it < 2; ++it) {
      const int kb8 = vkq0 * 8 + it * 16;
#pragma unroll
      for (int j = 0; j < 8; ++j) vreg[it * 8 + j] = vb[(size_t)(kb8 + j) * DV_];
    }
  };

  auto write_tiles = [&]() {
#pragma unroll
    for (int it = 0; it < 2; ++it) {
      const int row = (ktf >> 3) + it * 16;
      const int col8 = (ktf & 7) * 8;
      float xs[8] = {kreg[it * 2].x, kreg[it * 2].y, kreg[it * 2].z, kreg[it * 2].w,
                     kreg[it * 2 + 1].x, kreg[it * 2 + 1].y, kreg[it * 2 + 1].z,
                     kreg[it * 2 + 1].w};
      bf16x8 hi, lo;
      split8(xs, hi, lo);
      *reinterpret_cast<bf16x8*>(&Kl[khs][0][row][col8]) = hi;
      *reinterpret_cast<bf16x8*>(&Kl[khs][1][row][col8]) = lo;
    }
#pragma unroll
    for (int it = 0; it < 2; ++it) {
      const int kb8 = vkq0 * 8 + it * 16;
      const int col = kb8 ^ vswz;
      bf16x8 hi, lo;
      split8(&vreg[it * 8], hi, lo);
      *reinterpret_cast<bf16x8*>(&Vt[0][vdv][col]) = hi;
      *reinterpret_cast<bf16x8*>(&Vt[1][vdv][col]) = lo;
    }
  };

  const int nkt = (q0 + TQ) / TK;
  issue_loads(0);

  for (int kt = 0; kt < nkt; ++kt) {
    const int k0 = kt * TK;
    __syncthreads();  // LDS free (prev tile's reads done)
    write_tiles();
    __syncthreads();  // tile visible
    if (kt + 1 < nkt) issue_loads((kt + 1) * TK);  // T14: hide latency under compute

    if (k0 > qw + 15) continue;  // fully masked for this wave (barriers already passed)
    const bool needmask = (k0 + TK - 1 > qw);
    const int qglob = qw + li;
    bf16x8 AH[2], AL[2];

#pragma unroll
    for (int h = 0; h < 2; ++h) {
      // ---- K fragments (A-operand of S^T = K*Q^T) ----
      bf16x8 kf[2][2][2];  // [hl][ms][chunk]
#pragma unroll
      for (int hl = 0; hl < 2; ++hl)
#pragma unroll
        for (int ms = 0; ms < 2; ++ms)
#pragma unroll
          for (int c = 0; c < 2; ++c)
            kf[hl][ms][c] =
                *reinterpret_cast<const bf16x8*>(&Kl[h][hl][ms * 16 + li][c * 32 + g * 8]);

      f32x4 sT[2] = {zero4, zero4};
      __builtin_amdgcn_s_setprio(1);
#pragma unroll
      for (int ms = 0; ms < 2; ++ms)
#pragma unroll
        for (int c = 0; c < 2; ++c) {
          sT[ms] = __builtin_amdgcn_mfma_f32_16x16x32_bf16(kf[0][ms][c], qhi[h][c], sT[ms], 0, 0, 0);
          sT[ms] = __builtin_amdgcn_mfma_f32_16x16x32_bf16(kf[0][ms][c], qlo[h][c], sT[ms], 0, 0, 0);
          sT[ms] = __builtin_amdgcn_mfma_f32_16x16x32_bf16(kf[1][ms][c], qhi[h][c], sT[ms], 0, 0, 0);
        }
      __builtin_amdgcn_s_setprio(0);

      // ---- online ghostmax, head h (lane: q=li, k=16ms+4g+r) ----
      float sv[2][4];
#pragma unroll
      for (int ms = 0; ms < 2; ++ms)
#pragma unroll
        for (int r = 0; r < 4; ++r) {
          float v = sT[ms][r] * 0.125f;
          if (needmask && (k0 + ms * 16 + g * 4 + r > qglob)) v = -1e30f;
          sv[ms][r] = v;
        }
      float tmax = fmaxf(fmaxf(fmaxf(sv[0][0], sv[0][1]), fmaxf(sv[0][2], sv[0][3])),
                         fmaxf(fmaxf(sv[1][0], sv[1][1]), fmaxf(sv[1][2], sv[1][3])));
      tmax = fmaxf(tmax, __shfl_xor(tmax, 16));
      tmax = fmaxf(tmax, __shfl_xor(tmax, 32));

      if (__any(tmax > mreg[h] + 8.f)) {  // defer-max: rescale rarely fires
        const float mnew = fmaxf(mreg[h], tmax);
        const float fh = __expf(mreg[h] - mnew);
        mreg[h] = mnew;
        lreg[h] *= fh;
        float fr[4];
#pragma unroll
        for (int r = 0; r < 4; ++r) fr[r] = __shfl(fh, 20 * g + r);
#pragma unroll
        for (int d = 0; d < 8; ++d) {
          f32x4 o = Oacc[h][d];
          o[0] *= fr[0]; o[1] *= fr[1]; o[2] *= fr[2]; o[3] *= fr[3];
          Oacc[h][d] = o;
        }
      }

      float p[2][4], psum = 0.f;
#pragma unroll
      for (int ms = 0; ms < 2; ++ms)
#pragma unroll
        for (int r = 0; r < 4; ++r) {
          p[ms][r] = __expf(sv[ms][r] - mreg[h]);
          psum += p[ms][r];
        }
      psum += __shfl_xor(psum, 16);
      psum += __shfl_xor(psum, 32);
      lreg[h] += psum;

      // ---- P -> bf16 hi/lo through per-wave LDS slice (short idx == k) ----
      {
        union { unsigned uu[2]; bf16x8 dummy; } W;
        unsigned short h00 = f2bf(p[0][0]), h01 = f2bf(p[0][1]);
        unsigned short h02 = f2bf(p[0][2]), h03 = f2bf(p[0][3]);
        unsigned short h10 = f2bf(p[1][0]), h11 = f2bf(p[1][1]);
        unsigned short h12 = f2bf(p[1][2]), h13 = f2bf(p[1][3]);
        unsigned w0 = pack2(h00, h01), w1 = pack2(h02, h03);
        unsigned w2 = pack2(h10, h11), w3 = pack2(h12, h13);
        *reinterpret_cast<uint2*>(&Pex[w][li][g * 4]) = make_uint2(w0, w1);
        *reinterpret_cast<uint2*>(&Pex[w][li][16 + g * 4]) = make_uint2(w2, w3);
        float pl[2][4];
        pl[0][0] = p[0][0] - bf2f(h00); pl[0][1] = p[0][1] - bf2f(h01);
        pl[0][2] = p[0][2] - bf2f(h02); pl[0][3] = p[0][3] - bf2f(h03);
        pl[1][0] = p[1][0] - bf2f(h10); pl[1][1] = p[1][1] - bf2f(h11);
        pl[1][2] = p[1][2] - bf2f(h12); pl[1][3] = p[1][3] - bf2f(h13);
        unsigned l0 = pack2(f2bf(pl[0][0]), f2bf(pl[0][1]));
        unsigned l1 = pack2(f2bf(pl[0][2]), f2bf(pl[0][3]));
        unsigned l2 = pack2(f2bf(pl[1][0]), f2bf(pl[1][1]));
        unsigned l3 = pack2(f2bf(pl[1][2]), f2bf(pl[1][3]));
        *reinterpret_cast<uint2*>(&Pex[w][16 + li][g * 4]) = make_uint2(l0, l1);
        *reinterpret_cast<uint2*>(&Pex[w][16 + li][16 + g * 4]) = make_uint2(l2, l3);
        (void)W;
      }
      AH[h] = *reinterpret_cast<const bf16x8*>(&Pex[w][li][g * 8]);
      AL[h] = *reinterpret_cast<const bf16x8*>(&Pex[w][16 + li][g * 8]);
    }

    // ---- PV: O += P*V  (Ph*Vh + Pl*Vh + Ph*Vl) ----
    __builtin_amdgcn_s_setprio(1);
#pragma unroll
    for (int dvt = 0; dvt < 8; ++dvt) {
      const int dvr = dvt * 16 + li;
      const int vcol = (g * 8) ^ (((dvr >> 3) & 3) << 3);
      bf16x8 vh = *reinterpret_cast<const bf16x8*>(&Vt[0][dvr][vcol]);
      bf16x8 vl = *reinterpret_cast<const bf16x8*>(&Vt[1][dvr][vcol]);
#pragma unroll
      for (int h = 0; h < 2; ++h) {
        f32x4 acc = Oacc[h][dvt];
        acc = __builtin_amdgcn_mfma_f32_16x16x32_bf16(AH[h], vh, acc, 0, 0, 0);
        acc = __builtin_amdgcn_mfma_f32_16x16x32_bf16(AL[h], vh, acc, 0, 0, 0);
        acc = __builtin_amdgcn_mfma_f32_16x16x32_bf16(AH[h], vl, acc, 0, 0, 0);
        Oacc[h][dvt] = acc;
      }
    }
    __builtin_amdgcn_s_setprio(0);
  }

  // ---- epilogue: combine heads, store, fused GroupNorm partial stats ----
  float rl0[4], rl1[4];
#pragma unroll
  for (int r = 0; r < 4; ++r) {
    rl0[r] = 1.f / __shfl(lreg[0], 20 * g + r);
    rl1[r] = lam / __shfl(lreg[1], 20 * g + r);
  }
  float* ob = Obuf + ((size_t)(b * HP_ + hp)) * S_ * DV_;
  float lsum = 0.f, lss = 0.f;
#pragma unroll
  for (int dvt = 0; dvt < 8; ++dvt)
#pragma unroll
    for (int r = 0; r < 4; ++r) {
      float vres = Oacc[0][dvt][r] * rl0[r] - Oacc[1][dvt][r] * rl1[r];
      ob[(size_t)(qw + g * 4 + r) * DV_ + dvt * 16 + li] = vres;
      lsum += vres;
      lss += vres * vres;
    }
#pragma unroll
  for (int o = 1; o < 64; o <<= 1) {
    lsum += __shfl_xor(lsum, o);
    lss += __shfl_xor(lss, o);
  }
  if (l == 0) {
    redbuf[w * 2] = lsum;
    redbuf[w * 2 + 1] = lss;
  }
  __syncthreads();
  if (tid == 0) {
    const int region = ((b * HP_ + hp) << 1) | (q0 >= 1024 ? 1 : 0);
    atomicAdd(&stats[2 * region + 0], redbuf[0] + redbuf[2] + redbuf[4] + redbuf[6]);
    atomicAdd(&stats[2 * region + 1], redbuf[1] + redbuf[3] + redbuf[5] + redbuf[7]);
  }
}

// ---------------------------------------------------------------------------
// GroupNorm apply (stats from attn epilogue; 32 contiguous 131072-f regions).
// ---------------------------------------------------------------------------
__global__ void gn_apply(const float* __restrict__ O, const float* __restrict__ stats,
                         const float* __restrict__ gw, const float* __restrict__ gb,
                         float* __restrict__ out) {
  const size_t f = ((size_t)blockIdx.x * 256 + threadIdx.x) * 4;
  const int g = (int)(f >> 17);
  const int sidx = (int)((f >> 7) & 2047);
  const int hp = (int)((f >> 18) & 7);
  const int c = hp * 128 + (sidx >> 4);
  const float mean = stats[2 * g + 0] * (1.f / 131072.f);
  const float var = stats[2 * g + 1] * (1.f / 131072.f) - mean * mean;
  const float sc = rsqrtf(var + EPSV) * gw[c] * 0.2f;  // fold (1 - lambda_init)
  const float bi = gb[c] * 0.2f;
  float4 x = *reinterpret_cast<const float4*>(O + f);
  float4 y;
  y.x = (x.x - mean) * sc + bi;
  y.y = (x.y - mean) * sc + bi;
  y.z = (x.z - mean) * sc + bi;
  y.w = (x.w - mean) * sc + bi;
  *reinterpret_cast<float4*>(out + f) = y;
}

extern "C" void kernel_launch(void* const* d_in, const int* in_sizes, int n_in,
                              void* d_out, int out_size, void* d_ws, size_t ws_size,
                              hipStream_t stream) {
  const float* q = (const float*)d_in[0];
  const float* k = (const float*)d_in[1];
  const float* v = (const float*)d_in[2];
  const float* lq1 = (const float*)d_in[3];
  const float* lk1 = (const float*)d_in[4];
  const float* lq2 = (const float*)d_in[5];
  const float* lk2 = (const float*)d_in[6];
  const float* gw = (const float*)d_in[7];
  const float* gb = (const float*)d_in[8];
  float* out = (float*)d_out;

  float* Obuf = (float*)d_ws;  // [B][HP][S][DV] fp32 = 16 MiB
  float* stats = (float*)((char*)d_ws + (size_t)B_ * HP_ * S_ * DV_ * sizeof(float));

  hipMemsetAsync(stats, 0, 64 * sizeof(float), stream);
  diffattn_fwd<<<dim3(512), dim3(256), 0, stream>>>(q, k, v, lq1, lk1, lq2, lk2, Obuf, stats);
  gn_apply<<<dim3(4096), dim3(256), 0, stream>>>(Obuf, stats, gw, gb, out);
}